// Round 9
// baseline (521.573 us; speedup 1.0000x reference)
//
#include <hip/hip_runtime.h>
#include <hip/hip_bf16.h>

#define N_NODES 8192
#define NF      256
#define L2E     1.44269504088896341f

typedef __attribute__((ext_vector_type(8))) short short8;
typedef __attribute__((ext_vector_type(4))) short short4v;
typedef __attribute__((ext_vector_type(4))) float floatx4;

static __device__ __forceinline__ float bf2f(short s) {
    return __uint_as_float(((unsigned)(unsigned short)s) << 16);
}
static __device__ __forceinline__ short f2bf_rn(float f) {
    unsigned u = __float_as_uint(f) + 0x8000u;
    return (short)(u >> 16);
}
struct bfpair { short hi, lo; };
static __device__ __forceinline__ bfpair split_bf(float x) {
    bfpair p;
    p.hi = f2bf_rn(x);
    p.lo = f2bf_rn(x - bf2f(p.hi));
    return p;
}
// async global->LDS, 16B/lane, LDS dest = uniform base + lane*16
static __device__ __forceinline__ void async16(const void* g, void* l) {
    __builtin_amdgcn_global_load_lds(
        (const __attribute__((address_space(1))) unsigned*)g,
        (__attribute__((address_space(3))) unsigned*)l, 16, 0, 0);
}

// ---------------------------------------------------------------------------
// KX: split W (256x256 fp32) into bf16 hi/lo arrays, once.
// ---------------------------------------------------------------------------
__global__ __launch_bounds__(256) void kx_split(const float* __restrict__ W,
                                                short* __restrict__ Whi,
                                                short* __restrict__ Wlo) {
    #pragma unroll
    for (int e = 0; e < 4; ++e) {
        const int i = blockIdx.x * 1024 + e * 256 + threadIdx.x;
        bfpair p = split_bf(W[i]);
        Whi[i] = p.hi;
        Wlo[i] = p.lo;
    }
}

// ---------------------------------------------------------------------------
// K1: WhT[n][i] = sum_k X[i][k]*W[n][k] via hi/lo bf16 MFMA (fp32-accurate).
// ---------------------------------------------------------------------------
__global__ __launch_bounds__(512) void k1_gemm(const float* __restrict__ X,
                                               const short* __restrict__ Whi,
                                               const short* __restrict__ Wlo,
                                               const float* __restrict__ r,
                                               short* __restrict__ WhT,
                                               float* __restrict__ sp_src,
                                               float* __restrict__ sp_dst) {
    __shared__ float Xs[32 * 256];   // 32 KB; chunk slot = c ^ (row&7)

    const int tid = threadIdx.x;
    const int w = tid >> 6, lane = tid & 63;
    const int q = lane >> 4, m = lane & 15;
    const int rh = w >> 2, cq = w & 3;
    const int i_base = blockIdx.x * 32;

    // stage 32 rows of X (1 KB each); 4 instrs/wave
    #pragma unroll
    for (int v = 0; v < 4; ++v) {
        const int rowv = w * 4 + v;
        const int c = lane ^ (rowv & 7);
        async16(X + (size_t)(i_base + rowv) * NF + c * 4, &Xs[rowv * 256]);
    }
    __syncthreads();

    floatx4 acc[4] = {};
    const int xrow = rh * 16 + m;
    const int r7 = xrow & 7;
    #pragma unroll
    for (int ks = 0; ks < 8; ++ks) {
        const int c0 = ks * 8 + q * 2;
        float4 f0 = *(const float4*)(&Xs[xrow * 256 + ((c0 ^ r7) * 4)]);
        float4 f1 = *(const float4*)(&Xs[xrow * 256 + (((c0 + 1) ^ r7) * 4)]);
        const float xsv[8] = {f0.x, f0.y, f0.z, f0.w, f1.x, f1.y, f1.z, f1.w};
        short8 xh, xl;
        #pragma unroll
        for (int c = 0; c < 8; ++c) {
            bfpair p = split_bf(xsv[c]);
            xh[c] = p.hi; xl[c] = p.lo;
        }
        #pragma unroll
        for (int nt = 0; nt < 4; ++nt) {
            const int n = cq * 64 + nt * 16 + m;
            short8 wh = *(const short8*)(Whi + n * NF + ks * 32 + q * 8);
            short8 wl = *(const short8*)(Wlo + n * NF + ks * 32 + q * 8);
            acc[nt] = __builtin_amdgcn_mfma_f32_16x16x32_bf16(xh, wh, acc[nt], 0, 0, 0);
            acc[nt] = __builtin_amdgcn_mfma_f32_16x16x32_bf16(xl, wh, acc[nt], 0, 0, 0);
            acc[nt] = __builtin_amdgcn_mfma_f32_16x16x32_bf16(xh, wl, acc[nt], 0, 0, 0);
        }
    }

    // C/D layout: col = lane&15 (n), row = q*4 + reg (i)
    const int i0 = i_base + rh * 16 + q * 4;
    float vs[4] = {0.f, 0.f, 0.f, 0.f}, vd[4] = {0.f, 0.f, 0.f, 0.f};
    #pragma unroll
    for (int nt = 0; nt < 4; ++nt) {
        const int n = cq * 64 + nt * 16 + m;
        short4v v;
        #pragma unroll
        for (int r2 = 0; r2 < 4; ++r2) v[r2] = f2bf_rn(acc[nt][r2]);
        *(short4v*)(WhT + (size_t)n * N_NODES + i0) = v;
        const float rs = r[n], rd = r[NF + n];
        #pragma unroll
        for (int r2 = 0; r2 < 4; ++r2) {
            vs[r2] = fmaf(acc[nt][r2], rs, vs[r2]);
            vd[r2] = fmaf(acc[nt][r2], rd, vd[r2]);
        }
    }
    #pragma unroll
    for (int mask = 1; mask <= 8; mask <<= 1) {
        #pragma unroll
        for (int r2 = 0; r2 < 4; ++r2) {
            vs[r2] += __shfl_xor(vs[r2], mask);
            vd[r2] += __shfl_xor(vd[r2], mask);
        }
    }
    if (m == 0) {
        #pragma unroll
        for (int r2 = 0; r2 < 4; ++r2) {
            sp_src[cq * N_NODES + i0 + r2] = vs[r2];
            sp_dst[cq * N_NODES + i0 + r2] = vd[r2];
        }
    }
}

// ---------------------------------------------------------------------------
// K2: sum 4 partials -> s_src/s_dst; per-block max(s_dst) -> pmax[32]
// ---------------------------------------------------------------------------
__global__ __launch_bounds__(256) void k2_sv(const float* __restrict__ sp_src,
                                             const float* __restrict__ sp_dst,
                                             float* __restrict__ s_src,
                                             float* __restrict__ s_dst,
                                             float* __restrict__ pmax) {
    __shared__ float red[256];
    const int tid = threadIdx.x;
    const int i = blockIdx.x * 256 + tid;
    float ss = 0.f, sd = 0.f;
    #pragma unroll
    for (int nb = 0; nb < 4; ++nb) {
        ss += sp_src[nb * N_NODES + i];
        sd += sp_dst[nb * N_NODES + i];
    }
    s_src[i] = ss;
    s_dst[i] = sd;
    red[tid] = sd;
    __syncthreads();
    for (int off = 128; off > 0; off >>= 1) {
        if (tid < off) red[tid] = fmaxf(red[tid], red[tid + off]);
        __syncthreads();
    }
    if (tid == 0) pmax[blockIdx.x] = red[0];
}

// ---------------------------------------------------------------------------
// K3: pack A into a bitmask: mask[row][w] bit b = (A[row][w*32+b] != 0).
// One wave per row; per iter the wave reads 64 consecutive ints (256 B,
// coalesced) and __ballot packs them into one u64 (bit l <-> j=it*64+l,
// little-endian u64 store puts j 0-31 in word 2*it). HBM-bound: 256 MB read.
// ---------------------------------------------------------------------------
__global__ __launch_bounds__(512) void k3_bits(const int* __restrict__ Adj,
                                               unsigned* __restrict__ mask) {
    const int w = threadIdx.x >> 6, lane = threadIdx.x & 63;
    const int row = blockIdx.x * 8 + w;
    const int* Ar = Adj + (size_t)row * N_NODES;
    unsigned long long* Mr = (unsigned long long*)(mask + (size_t)row * 256);
    for (int it = 0; it < 128; ++it) {
        const int v = Ar[it * 64 + lane];
        const unsigned long long b = __ballot(v != 0);
        if (lane == 0) Mr[it] = b;
    }
}

// ---------------------------------------------------------------------------
// K4 v9: r8 structure with the VMEM diet cut 2.7x.
// Invariant across r3/r5/r7/r8: ~0.55-0.6 P-cells/cyc/CU = per-CU VMEM
// request/return pipe saturated (12-14 B/cyc/lane-returned; scattered lines
// worse — r6). A (64 B/lane/step, 32 lines/instr) and t (64 B/lane/step)
// were 2/3 of the bytes. This version: A -> 8 B/lane/step (uint2 bitmask,
// bit-identical predicate), t -> LDS (staged once, 8 KB; ds_read broadcast,
// off the VMEM pipe). B staging, 8-wave domain, schedule, MFMA mapping,
// epilogue, and fp order unchanged from r8. Per step: [4 stage DMA] ->
// [1 mask prefetch] -> t ds_reads + pgroup + 16 MFMA -> vmcnt(1) (drains
// DMAs, mask rides) -> s_barrier. LDS 64+8=72 KB -> 2 blocks/CU.
// ---------------------------------------------------------------------------
static __device__ __forceinline__ void pgroupb(const unsigned bits, const int sh,
                                               const floatx4 t,
                                               const float s_i, const float d_i,
                                               float* p) {
    #pragma unroll
    for (int c = 0; c < 4; ++c) {
        float sum = s_i + t[c];
        float lr  = fmaxf(sum, 0.2f * sum);
        float pp  = __builtin_amdgcn_exp2f(fmaf(lr, L2E, d_i));
        p[c] = ((bits >> (sh + c)) & 1u) ? pp : 0.0f;
    }
}

__global__ __launch_bounds__(512, 4) void k4_attn(const unsigned* __restrict__ Abits,
                                                  const short* __restrict__ WhT,
                                                  const float* __restrict__ s_dst,
                                                  const float* __restrict__ s_src,
                                                  const float* __restrict__ pmax,
                                                  float* __restrict__ pden,
                                                  float* __restrict__ outacc) {
    __shared__ short Bs[2][256][64];    // [buf][n][64 j]; 16B slot = c^(n&7); 64 KB
    __shared__ float ts[2048];          // this block's j-quarter of s_dst; 8 KB

    const int tid = threadIdx.x;
    const int w = tid >> 6, lane = tid & 63;
    const int q = lane >> 4, m = lane & 15;
    const int rh = w >> 1, ch = w & 1;      // 4 rowgroups x 2 n-halves
    const int ib = blockIdx.x & 127;        // row group (64 rows)
    const int jh = blockIdx.x >> 7;         // j quarter (0..3)
    const int i0 = ib * 64;
    const int jbase = jh * 2048;
    const int row = i0 + rh * 16 + m;
    const int q8 = q * 8;

    float M = pmax[0];
    #pragma unroll
    for (int b = 1; b < 32; ++b) M = fmaxf(M, pmax[b]);
    const float s_i = s_src[row];
    const float e0 = s_i + M;
    const float d_i = -fmaxf(e0, 0.2f * e0) * L2E;   // -c_i*log2e, c_i >= row max

    // ---- B staging: wave stages n-rows [w*32, w*32+32) via 4 DMA instrs ----
    const int srow = lane >> 3;
    const int scc = (lane & 7) ^ srow;
    const short* gB[4];
    #pragma unroll
    for (int v = 0; v < 4; ++v)
        gB[v] = WhT + (size_t)(w * 32 + v * 8 + srow) * N_NODES + jbase + scc * 8;

    // ---- bitmask pointer: uint2 per step (64 j-bits for this row) ----
    const unsigned* Mp = Abits + (size_t)row * 256 + (jbase >> 5);

    floatx4 acc[8];
    #pragma unroll
    for (int nt = 0; nt < 8; ++nt) acc[nt] = (floatx4){0.f, 0.f, 0.f, 0.f};
    float den = 0.f;

    // prologue: stage t-quarter (1 DMA/wave) + B step 0 + mask(0) prefetch
    async16(s_dst + jbase + w * 256 + lane * 4, &ts[w * 256]);
    #pragma unroll
    for (int v = 0; v < 4; ++v)
        async16(gB[v], &Bs[0][w * 32 + v * 8][0]);
    uint2 mk = *(const uint2*)(Mp);
    __syncthreads();

    for (int s = 0; s < 32; ++s) {
        const int cur = s & 1;

        // 1) stage next tile into other buffer (the 4 OLDEST vmem ops)
        short* dstb = &Bs[cur ^ 1][0][0];
        const int gn = ((s + 1) & 31) * 64;
        #pragma unroll
        for (int v = 0; v < 4; ++v)
            async16(gB[v] + gn, dstb + (w * 32 + v * 8) * 64);
        __builtin_amdgcn_sched_barrier(0);

        // 2) prefetch next step's mask (1 x 8 B; the NEWEST — rides barrier)
        uint2 nmk = *(const uint2*)(Mp + ((s + 1) & 31) * 2);
        __builtin_amdgcn_sched_barrier(0);

        // 3) t from LDS (broadcast ds_read_b128 x4, lgkm pipe — off VMEM)
        const int gt = s * 64;
        floatx4 t0 = *(const floatx4*)(ts + gt + q8);
        floatx4 t1 = *(const floatx4*)(ts + gt + q8 + 4);
        floatx4 t2 = *(const floatx4*)(ts + gt + 32 + q8);
        floatx4 t3 = *(const floatx4*)(ts + gt + 32 + q8 + 4);

        // 4) P: 16 j per lane (slice0 j=q8+0..7, slice1 j=32+q8+0..7)
        float p[16];
        pgroupb(mk.x, q8,     t0, s_i, d_i, p);
        pgroupb(mk.x, q8 + 4, t1, s_i, d_i, p + 4);
        pgroupb(mk.y, q8,     t2, s_i, d_i, p + 8);
        pgroupb(mk.y, q8 + 4, t3, s_i, d_i, p + 12);

        short8 af0, af1;
        #pragma unroll
        for (int c = 0; c < 8; ++c) { af0[c] = f2bf_rn(p[c]); af1[c] = f2bf_rn(p[8 + c]); }
        #pragma unroll
        for (int c = 0; c < 16; ++c) den += p[c];

        // 5) PV: 8 nt x 2 k-slices = 16 MFMAs
        const short* Bb = &Bs[cur][0][0];
        __builtin_amdgcn_s_setprio(1);
        #pragma unroll
        for (int nt = 0; nt < 8; ++nt) {
            const int n = ch * 128 + nt * 16 + m;
            const int sw = m & 7;
            short8 b0 = *(const short8*)(Bb + n * 64 + ((q ^ sw) * 8));
            short8 b1 = *(const short8*)(Bb + n * 64 + (((4 + q) ^ sw) * 8));
            acc[nt] = __builtin_amdgcn_mfma_f32_16x16x32_bf16(af0, b0, acc[nt], 0, 0, 0);
            acc[nt] = __builtin_amdgcn_mfma_f32_16x16x32_bf16(af1, b1, acc[nt], 0, 0, 0);
        }
        __builtin_amdgcn_s_setprio(0);

        // 6) counted wait: drain the 4 stage DMAs; mask prefetch stays in flight
        __builtin_amdgcn_sched_barrier(0);
        asm volatile("s_waitcnt vmcnt(1)" ::: "memory");
        __builtin_amdgcn_s_barrier();

        mk = nmk;
    }

    // ---- epilogue: barrier-free. den: reduce over q (4 lanes per row) ----
    den += __shfl_xor(den, 16);
    den += __shfl_xor(den, 32);
    if (ch == 0 && q == 0) pden[jh * N_NODES + row] = den;

    // out: each (row,n) owned by exactly one wave here; 4-way across jh blocks
    #pragma unroll
    for (int nt = 0; nt < 8; ++nt) {
        #pragma unroll
        for (int rg = 0; rg < 4; ++rg) {
            const int orow = i0 + rh * 16 + q * 4 + rg;
            const int n = ch * 128 + nt * 16 + m;
            atomicAdd(&outacc[(size_t)orow * NF + n], acc[nt][rg]);
        }
    }
}

// ---------------------------------------------------------------------------
// K5: out = gelu(outacc / sum_{jh<4} pden[jh]), in place. 8 elems/thread.
// ---------------------------------------------------------------------------
__global__ __launch_bounds__(256) void k5_fin(const float* __restrict__ pden,
                                              float* __restrict__ out) {
    const int gid = blockIdx.x * 256 + threadIdx.x;
    const int row = gid >> 5;
    const int c0 = (gid & 31) * 8;
    const float d = (pden[row] + pden[N_NODES + row]) +
                    (pden[2 * N_NODES + row] + pden[3 * N_NODES + row]);
    const float inv = 1.0f / fmaxf(d, 1e-30f);
    float* p = out + (size_t)row * NF + c0;
    float4 v0 = *(const float4*)(p);
    float4 v1 = *(const float4*)(p + 4);
    float xs[8] = {v0.x, v0.y, v0.z, v0.w, v1.x, v1.y, v1.z, v1.w};
    #pragma unroll
    for (int c = 0; c < 8; ++c) {
        const float x = xs[c] * inv;
        xs[c] = 0.5f * x * (1.0f + erff(x * 0.70710678118f)); // exact GELU
    }
    *(float4*)(p)     = (float4){xs[0], xs[1], xs[2], xs[3]};
    *(float4*)(p + 4) = (float4){xs[4], xs[5], xs[6], xs[7]};
}

// ---------------------------------------------------------------------------
extern "C" void kernel_launch(void* const* d_in, const int* in_sizes, int n_in,
                              void* d_out, int out_size, void* d_ws, size_t ws_size,
                              hipStream_t stream) {
    const float* X = (const float*)d_in[0];   // fp32 8192x256
    const int*   A = (const int*)d_in[1];     // int32 8192x8192
    const float* W = (const float*)d_in[2];   // fp32 256x256
    const float* r = (const float*)d_in[3];   // fp32 512
    float* out = (float*)d_out;

    // ws: WhT bf16 4MB | Whi 128K | Wlo 128K | sp_src 128K | sp_dst 128K |
    //     s_src 32K | s_dst 32K | pmax 128B | Abits 8MB
    // pden (4*8192 f32 = 128K) ALIASES sp_src (k2 consumes it before k4).
    char* wsp = (char*)d_ws;
    short* WhT    = (short*)wsp;                    wsp += (size_t)NF * N_NODES * 2;
    short* Whi    = (short*)wsp;                    wsp += NF * NF * 2;
    short* Wlo    = (short*)wsp;                    wsp += NF * NF * 2;
    float* sp_src = (float*)wsp;                    wsp += 4 * N_NODES * 4;
    float* sp_dst = (float*)wsp;                    wsp += 4 * N_NODES * 4;
    float* s_src  = (float*)wsp;                    wsp += N_NODES * 4;
    float* s_dst  = (float*)wsp;                    wsp += N_NODES * 4;
    float* pmax   = (float*)wsp;                    wsp += 256;
    unsigned* Abits = (unsigned*)wsp;               // 8 MB
    float* pden   = sp_src;

    hipMemsetAsync(out, 0, (size_t)N_NODES * NF * 4, stream);
    kx_split<<<64, 256, 0, stream>>>(W, Whi, Wlo);
    k1_gemm<<<256, 512, 0, stream>>>(X, Whi, Wlo, r, WhT, sp_src, sp_dst);
    k2_sv<<<32, 256, 0, stream>>>(sp_src, sp_dst, s_src, s_dst, pmax);
    k3_bits<<<1024, 512, 0, stream>>>(A, Abits);
    k4_attn<<<512, 512, 0, stream>>>(Abits, WhT, s_dst, s_src, pmax, pden, out);
    k5_fin<<<1024, 256, 0, stream>>>(pden, out);
}

// Round 10
// 482.820 us; speedup vs baseline: 1.0803x; 1.0803x over previous
//
#include <hip/hip_runtime.h>
#include <hip/hip_bf16.h>

#define N_NODES 8192
#define NF      256
#define L2E     1.44269504088896341f

typedef __attribute__((ext_vector_type(8))) short short8;
typedef __attribute__((ext_vector_type(4))) short short4v;
typedef __attribute__((ext_vector_type(4))) float floatx4;

static __device__ __forceinline__ float bf2f(short s) {
    return __uint_as_float(((unsigned)(unsigned short)s) << 16);
}
static __device__ __forceinline__ short f2bf_rn(float f) {
    unsigned u = __float_as_uint(f) + 0x8000u;
    return (short)(u >> 16);
}
struct bfpair { short hi, lo; };
static __device__ __forceinline__ bfpair split_bf(float x) {
    bfpair p;
    p.hi = f2bf_rn(x);
    p.lo = f2bf_rn(x - bf2f(p.hi));
    return p;
}
// async global->LDS, 16B/lane, LDS dest = uniform base + lane*16
static __device__ __forceinline__ void async16(const void* g, void* l) {
    __builtin_amdgcn_global_load_lds(
        (const __attribute__((address_space(1))) unsigned*)g,
        (__attribute__((address_space(3))) unsigned*)l, 16, 0, 0);
}

// ---------------------------------------------------------------------------
// KX: split W (256x256 fp32) into bf16 hi/lo arrays, once.
// ---------------------------------------------------------------------------
__global__ __launch_bounds__(256) void kx_split(const float* __restrict__ W,
                                                short* __restrict__ Whi,
                                                short* __restrict__ Wlo) {
    #pragma unroll
    for (int e = 0; e < 4; ++e) {
        const int i = blockIdx.x * 1024 + e * 256 + threadIdx.x;
        bfpair p = split_bf(W[i]);
        Whi[i] = p.hi;
        Wlo[i] = p.lo;
    }
}

// ---------------------------------------------------------------------------
// K1: WhT[n][i] = sum_k X[i][k]*W[n][k] via hi/lo bf16 MFMA (fp32-accurate).
// ---------------------------------------------------------------------------
__global__ __launch_bounds__(512) void k1_gemm(const float* __restrict__ X,
                                               const short* __restrict__ Whi,
                                               const short* __restrict__ Wlo,
                                               const float* __restrict__ r,
                                               short* __restrict__ WhT,
                                               float* __restrict__ sp_src,
                                               float* __restrict__ sp_dst) {
    __shared__ float Xs[32 * 256];   // 32 KB; chunk slot = c ^ (row&7)

    const int tid = threadIdx.x;
    const int w = tid >> 6, lane = tid & 63;
    const int q = lane >> 4, m = lane & 15;
    const int rh = w >> 2, cq = w & 3;
    const int i_base = blockIdx.x * 32;

    // stage 32 rows of X (1 KB each); 4 instrs/wave
    #pragma unroll
    for (int v = 0; v < 4; ++v) {
        const int rowv = w * 4 + v;
        const int c = lane ^ (rowv & 7);
        async16(X + (size_t)(i_base + rowv) * NF + c * 4, &Xs[rowv * 256]);
    }
    __syncthreads();

    floatx4 acc[4] = {};
    const int xrow = rh * 16 + m;
    const int r7 = xrow & 7;
    #pragma unroll
    for (int ks = 0; ks < 8; ++ks) {
        const int c0 = ks * 8 + q * 2;
        float4 f0 = *(const float4*)(&Xs[xrow * 256 + ((c0 ^ r7) * 4)]);
        float4 f1 = *(const float4*)(&Xs[xrow * 256 + (((c0 + 1) ^ r7) * 4)]);
        const float xsv[8] = {f0.x, f0.y, f0.z, f0.w, f1.x, f1.y, f1.z, f1.w};
        short8 xh, xl;
        #pragma unroll
        for (int c = 0; c < 8; ++c) {
            bfpair p = split_bf(xsv[c]);
            xh[c] = p.hi; xl[c] = p.lo;
        }
        #pragma unroll
        for (int nt = 0; nt < 4; ++nt) {
            const int n = cq * 64 + nt * 16 + m;
            short8 wh = *(const short8*)(Whi + n * NF + ks * 32 + q * 8);
            short8 wl = *(const short8*)(Wlo + n * NF + ks * 32 + q * 8);
            acc[nt] = __builtin_amdgcn_mfma_f32_16x16x32_bf16(xh, wh, acc[nt], 0, 0, 0);
            acc[nt] = __builtin_amdgcn_mfma_f32_16x16x32_bf16(xl, wh, acc[nt], 0, 0, 0);
            acc[nt] = __builtin_amdgcn_mfma_f32_16x16x32_bf16(xh, wl, acc[nt], 0, 0, 0);
        }
    }

    // C/D layout: col = lane&15 (n), row = q*4 + reg (i)
    const int i0 = i_base + rh * 16 + q * 4;
    float vs[4] = {0.f, 0.f, 0.f, 0.f}, vd[4] = {0.f, 0.f, 0.f, 0.f};
    #pragma unroll
    for (int nt = 0; nt < 4; ++nt) {
        const int n = cq * 64 + nt * 16 + m;
        short4v v;
        #pragma unroll
        for (int r2 = 0; r2 < 4; ++r2) v[r2] = f2bf_rn(acc[nt][r2]);
        *(short4v*)(WhT + (size_t)n * N_NODES + i0) = v;
        const float rs = r[n], rd = r[NF + n];
        #pragma unroll
        for (int r2 = 0; r2 < 4; ++r2) {
            vs[r2] = fmaf(acc[nt][r2], rs, vs[r2]);
            vd[r2] = fmaf(acc[nt][r2], rd, vd[r2]);
        }
    }
    #pragma unroll
    for (int mask = 1; mask <= 8; mask <<= 1) {
        #pragma unroll
        for (int r2 = 0; r2 < 4; ++r2) {
            vs[r2] += __shfl_xor(vs[r2], mask);
            vd[r2] += __shfl_xor(vd[r2], mask);
        }
    }
    if (m == 0) {
        #pragma unroll
        for (int r2 = 0; r2 < 4; ++r2) {
            sp_src[cq * N_NODES + i0 + r2] = vs[r2];
            sp_dst[cq * N_NODES + i0 + r2] = vd[r2];
        }
    }
}

// ---------------------------------------------------------------------------
// K2: sum 4 partials -> s_src/s_dst; per-block max(s_dst) -> pmax[32]
// ---------------------------------------------------------------------------
__global__ __launch_bounds__(256) void k2_sv(const float* __restrict__ sp_src,
                                             const float* __restrict__ sp_dst,
                                             float* __restrict__ s_src,
                                             float* __restrict__ s_dst,
                                             float* __restrict__ pmax) {
    __shared__ float red[256];
    const int tid = threadIdx.x;
    const int i = blockIdx.x * 256 + tid;
    float ss = 0.f, sd = 0.f;
    #pragma unroll
    for (int nb = 0; nb < 4; ++nb) {
        ss += sp_src[nb * N_NODES + i];
        sd += sp_dst[nb * N_NODES + i];
    }
    s_src[i] = ss;
    s_dst[i] = sd;
    red[tid] = sd;
    __syncthreads();
    for (int off = 128; off > 0; off >>= 1) {
        if (tid < off) red[tid] = fmaxf(red[tid], red[tid + off]);
        __syncthreads();
    }
    if (tid == 0) pmax[blockIdx.x] = red[0];
}

// ---------------------------------------------------------------------------
// K3 v2: per-thread bit-packing (r9's ballot loop was latency-bound, ~75 us).
// One u32 word per thread (2M threads, 8192 blocks): 8 independent int4
// loads (32 consecutive ints = 128 B/thread, wave reads 8 KB contiguous).
// mask[gid] bit b = (A[gid*32+b] != 0) — identical layout to r9's ballot.
// ---------------------------------------------------------------------------
__global__ __launch_bounds__(256) void k3_bits(const int* __restrict__ Adj,
                                               unsigned* __restrict__ mask) {
    const int gid = blockIdx.x * 256 + threadIdx.x;   // word index, 2M total
    const int4* src = (const int4*)Adj + (size_t)gid * 8;
    unsigned b = 0;
    #pragma unroll
    for (int c = 0; c < 8; ++c) {
        const int4 v = src[c];
        b |= (v.x != 0 ? 1u : 0u) << (c * 4);
        b |= (v.y != 0 ? 1u : 0u) << (c * 4 + 1);
        b |= (v.z != 0 ? 1u : 0u) << (c * 4 + 2);
        b |= (v.w != 0 ? 1u : 0u) << (c * 4 + 3);
    }
    mask[gid] = b;
}

// ---------------------------------------------------------------------------
// K4 v10: 128 rows/block, 8 waves, no ch-duplication.
// r8/r9 evidence: per-block-step cost pinned at ~5.8K cyc regardless of
// payload -> amortize: halve block-steps (16384 -> 8192) by doubling rows.
// grid 512 = 64 row-groups(128 rows) x 8 j-eighths (1024 j = 16 steps x 64).
// 512 thr = 8 waves; wave w = row-group rh (16 rows), owns FULL n=256
// (acc[16], 32 MFMA/step) -> pgroup computed ONCE chip-wide (r9 was 2x).
// B L2 traffic halves (512->256 MB). Microstructure identical to r9:
// [4 stage DMA]->[1 mask prefetch]->t(LDS)+pgroup+MFMA(setprio) x2 slices->
// vmcnt(1) (drains DMAs, mask rides)->s_barrier. LDS 64+4=68 KB -> 2 blk/CU.
// Out: exactly-8-way f32 atomicAdd into zeroed out (order-independent);
// pden[8][8192] aliases sp_src+sp_dst (256 KB, both dead after k2).
// ---------------------------------------------------------------------------
static __device__ __forceinline__ void pgroupb(const unsigned bits, const int sh,
                                               const floatx4 t,
                                               const float s_i, const float d_i,
                                               float* p) {
    #pragma unroll
    for (int c = 0; c < 4; ++c) {
        float sum = s_i + t[c];
        float lr  = fmaxf(sum, 0.2f * sum);
        float pp  = __builtin_amdgcn_exp2f(fmaf(lr, L2E, d_i));
        p[c] = ((bits >> (sh + c)) & 1u) ? pp : 0.0f;
    }
}

__global__ __launch_bounds__(512, 4) void k4_attn(const unsigned* __restrict__ Abits,
                                                  const short* __restrict__ WhT,
                                                  const float* __restrict__ s_dst,
                                                  const float* __restrict__ s_src,
                                                  const float* __restrict__ pmax,
                                                  float* __restrict__ pden,
                                                  float* __restrict__ outacc) {
    __shared__ short Bs[2][256][64];    // [buf][n][64 j]; 16B slot = c^(n&7); 64 KB
    __shared__ float ts[1024];          // this block's j-eighth of s_dst; 4 KB

    const int tid = threadIdx.x;
    const int w = tid >> 6, lane = tid & 63;
    const int q = lane >> 4, m = lane & 15;
    const int rh = w;                       // 8 row-groups of 16 rows
    const int ib = blockIdx.x & 63;         // row group (128 rows)
    const int jh = blockIdx.x >> 6;         // j eighth (0..7)
    const int i0 = ib * 128;
    const int jbase = jh * 1024;
    const int row = i0 + rh * 16 + m;
    const int q8 = q * 8;

    float M = pmax[0];
    #pragma unroll
    for (int b = 1; b < 32; ++b) M = fmaxf(M, pmax[b]);
    const float s_i = s_src[row];
    const float e0 = s_i + M;
    const float d_i = -fmaxf(e0, 0.2f * e0) * L2E;   // -c_i*log2e, c_i >= row max

    // ---- B staging: wave stages n-rows [w*32, w*32+32) via 4 DMA instrs ----
    const int srow = lane >> 3;
    const int scc = (lane & 7) ^ srow;
    const short* gB[4];
    #pragma unroll
    for (int v = 0; v < 4; ++v)
        gB[v] = WhT + (size_t)(w * 32 + v * 8 + srow) * N_NODES + jbase + scc * 8;

    // ---- bitmask pointer: uint2 per step (64 j-bits for this row) ----
    const unsigned* Mp = Abits + (size_t)row * 256 + (jbase >> 5);

    floatx4 acc[16];
    #pragma unroll
    for (int nt = 0; nt < 16; ++nt) acc[nt] = (floatx4){0.f, 0.f, 0.f, 0.f};
    float den = 0.f;

    // prologue: stage t-eighth (4 KB, waves 0-3) + B step 0 + mask(0) prefetch
    if (w < 4) async16(s_dst + jbase + w * 256 + lane * 4, &ts[w * 256]);
    #pragma unroll
    for (int v = 0; v < 4; ++v)
        async16(gB[v], &Bs[0][w * 32 + v * 8][0]);
    uint2 mk = *(const uint2*)(Mp);
    __syncthreads();

    for (int s = 0; s < 16; ++s) {
        const int cur = s & 1;

        // 1) stage next tile into other buffer (the 4 OLDEST vmem ops)
        short* dstb = &Bs[cur ^ 1][0][0];
        const int gn = ((s + 1) & 15) * 64;
        #pragma unroll
        for (int v = 0; v < 4; ++v)
            async16(gB[v] + gn, dstb + (w * 32 + v * 8) * 64);
        __builtin_amdgcn_sched_barrier(0);

        // 2) prefetch next step's mask (1 x 8 B; the NEWEST — rides barrier)
        uint2 nmk = *(const uint2*)(Mp + ((s + 1) & 15) * 2);
        __builtin_amdgcn_sched_barrier(0);

        const int gt = s * 64;
        const short* Bb = &Bs[cur][0][0];
        const int sw = m & 7;

        // ---- k-slice 0 (j = gt + q8 + 0..7) ----
        {
            floatx4 t0 = *(const floatx4*)(ts + gt + q8);
            floatx4 t1 = *(const floatx4*)(ts + gt + q8 + 4);
            float p[8];
            pgroupb(mk.x, q8,     t0, s_i, d_i, p);
            pgroupb(mk.x, q8 + 4, t1, s_i, d_i, p + 4);
            short8 af0;
            #pragma unroll
            for (int c = 0; c < 8; ++c) { af0[c] = f2bf_rn(p[c]); den += p[c]; }
            __builtin_amdgcn_s_setprio(1);
            #pragma unroll
            for (int nt = 0; nt < 16; ++nt) {
                const int n = nt * 16 + m;
                short8 b0 = *(const short8*)(Bb + n * 64 + ((q ^ sw) * 8));
                acc[nt] = __builtin_amdgcn_mfma_f32_16x16x32_bf16(af0, b0, acc[nt], 0, 0, 0);
            }
            __builtin_amdgcn_s_setprio(0);
        }
        // ---- k-slice 1 (j = gt + 32 + q8 + 0..7) ----
        {
            floatx4 t2 = *(const floatx4*)(ts + gt + 32 + q8);
            floatx4 t3 = *(const floatx4*)(ts + gt + 32 + q8 + 4);
            float p[8];
            pgroupb(mk.y, q8,     t2, s_i, d_i, p);
            pgroupb(mk.y, q8 + 4, t3, s_i, d_i, p + 4);
            short8 af1;
            #pragma unroll
            for (int c = 0; c < 8; ++c) { af1[c] = f2bf_rn(p[c]); den += p[c]; }
            __builtin_amdgcn_s_setprio(1);
            #pragma unroll
            for (int nt = 0; nt < 16; ++nt) {
                const int n = nt * 16 + m;
                short8 b1 = *(const short8*)(Bb + n * 64 + (((4 + q) ^ sw) * 8));
                acc[nt] = __builtin_amdgcn_mfma_f32_16x16x32_bf16(af1, b1, acc[nt], 0, 0, 0);
            }
            __builtin_amdgcn_s_setprio(0);
        }

        // 3) counted wait: drain the 4 stage DMAs; mask prefetch stays in flight
        __builtin_amdgcn_sched_barrier(0);
        asm volatile("s_waitcnt vmcnt(1)" ::: "memory");
        __builtin_amdgcn_s_barrier();

        mk = nmk;
    }

    // ---- epilogue: barrier-free. den: reduce over q (4 lanes per row) ----
    den += __shfl_xor(den, 16);
    den += __shfl_xor(den, 32);
    if (q == 0) pden[jh * N_NODES + row] = den;

    // out: each (row,n) owned by exactly one wave; 8-way across jh blocks
    #pragma unroll
    for (int nt = 0; nt < 16; ++nt) {
        #pragma unroll
        for (int rg = 0; rg < 4; ++rg) {
            const int orow = i0 + rh * 16 + q * 4 + rg;
            const int n = nt * 16 + m;
            atomicAdd(&outacc[(size_t)orow * NF + n], acc[nt][rg]);
        }
    }
}

// ---------------------------------------------------------------------------
// K5: out = gelu(outacc / sum_{jh<8} pden[jh]), in place. 8 elems/thread.
// ---------------------------------------------------------------------------
__global__ __launch_bounds__(256) void k5_fin(const float* __restrict__ pden,
                                              float* __restrict__ out) {
    const int gid = blockIdx.x * 256 + threadIdx.x;
    const int row = gid >> 5;
    const int c0 = (gid & 31) * 8;
    const float d = ((pden[row] + pden[N_NODES + row]) +
                     (pden[2 * N_NODES + row] + pden[3 * N_NODES + row])) +
                    ((pden[4 * N_NODES + row] + pden[5 * N_NODES + row]) +
                     (pden[6 * N_NODES + row] + pden[7 * N_NODES + row]));
    const float inv = 1.0f / fmaxf(d, 1e-30f);
    float* p = out + (size_t)row * NF + c0;
    float4 v0 = *(const float4*)(p);
    float4 v1 = *(const float4*)(p + 4);
    float xs[8] = {v0.x, v0.y, v0.z, v0.w, v1.x, v1.y, v1.z, v1.w};
    #pragma unroll
    for (int c = 0; c < 8; ++c) {
        const float x = xs[c] * inv;
        xs[c] = 0.5f * x * (1.0f + erff(x * 0.70710678118f)); // exact GELU
    }
    *(float4*)(p)     = (float4){xs[0], xs[1], xs[2], xs[3]};
    *(float4*)(p + 4) = (float4){xs[4], xs[5], xs[6], xs[7]};
}

// ---------------------------------------------------------------------------
extern "C" void kernel_launch(void* const* d_in, const int* in_sizes, int n_in,
                              void* d_out, int out_size, void* d_ws, size_t ws_size,
                              hipStream_t stream) {
    const float* X = (const float*)d_in[0];   // fp32 8192x256
    const int*   A = (const int*)d_in[1];     // int32 8192x8192
    const float* W = (const float*)d_in[2];   // fp32 256x256
    const float* r = (const float*)d_in[3];   // fp32 512
    float* out = (float*)d_out;

    // ws: WhT bf16 4MB | Whi 128K | Wlo 128K | sp_src 128K | sp_dst 128K |
    //     s_src 32K | s_dst 32K | pmax 128B | Abits 8MB
    // pden (8*8192 f32 = 256K) ALIASES sp_src+sp_dst exactly (both fully
    // consumed by k2 before k4 writes pden; stream-ordered).
    char* wsp = (char*)d_ws;
    short* WhT    = (short*)wsp;                    wsp += (size_t)NF * N_NODES * 2;
    short* Whi    = (short*)wsp;                    wsp += NF * NF * 2;
    short* Wlo    = (short*)wsp;                    wsp += NF * NF * 2;
    float* sp_src = (float*)wsp;                    wsp += 4 * N_NODES * 4;
    float* sp_dst = (float*)wsp;                    wsp += 4 * N_NODES * 4;
    float* s_src  = (float*)wsp;                    wsp += N_NODES * 4;
    float* s_dst  = (float*)wsp;                    wsp += N_NODES * 4;
    float* pmax   = (float*)wsp;                    wsp += 256;
    unsigned* Abits = (unsigned*)wsp;               // 8 MB
    float* pden   = sp_src;                         // spans sp_src + sp_dst

    hipMemsetAsync(out, 0, (size_t)N_NODES * NF * 4, stream);
    kx_split<<<64, 256, 0, stream>>>(W, Whi, Wlo);
    k1_gemm<<<256, 512, 0, stream>>>(X, Whi, Wlo, r, WhT, sp_src, sp_dst);
    k2_sv<<<32, 256, 0, stream>>>(sp_src, sp_dst, s_src, s_dst, pmax);
    k3_bits<<<8192, 256, 0, stream>>>(A, Abits);
    k4_attn<<<512, 512, 0, stream>>>(Abits, WhT, s_dst, s_src, pmax, pden, out);
    k5_fin<<<1024, 256, 0, stream>>>(pden, out);
}